// Round 6
// baseline (78382.837 us; speedup 1.0000x reference)
//
#include <hip/hip_runtime.h>

#define ALPHA 0.9f
#define THRESH 1.0f
#define BATCH 512
#define CIN 16
#define TSTEPS 2000
#define NRES 1024
#define NCLS 10

#define NGROUP 32       // 32 batch groups of 16 rows
#define BPG 8           // blocks per group, 128 neurons each

typedef int   v4i __attribute__((ext_vector_type(4)));
typedef float v4f __attribute__((ext_vector_type(4)));
typedef short v8s __attribute__((ext_vector_type(8)));

// ---- ws layout (bytes) ----
#define CTR_OFF    0        // 32 groups x 2 parities x 128 B barrier counters (8 KB)
#define SLOTC_OFF  8192     // max|W_clf| bits
#define ROWMAX_OFF 9216     // per-row max|W_res[n][:]|, 1024 floats (4 KB)
#define MASK_OFF   16384    // spike masks: 2 x 32 x 16 x 128 B = 128 KB
#define WQF_OFF    147456   // W_res int8, MFMA-fragment order: 1 MB
#define WCF_OFF    1196032  // W_clf int8 fragment tile: 16 KB
#define LDS_BYTES  (131072 + 16*1040 + 1024)   // B slice + A image + xA image

__global__ __launch_bounds__(256) void maxabs_kernel(const float* __restrict__ W,
                                                     int n, unsigned* __restrict__ slot) {
    unsigned m = 0u;
    for (int i = blockIdx.x * 256 + threadIdx.x; i < n; i += gridDim.x * 256)
        m = max(m, __float_as_uint(W[i]) & 0x7fffffffu);
#pragma unroll
    for (int off = 32; off >= 1; off >>= 1)
        m = max(m, (unsigned)__shfl_xor((int)m, off, 64));
    if ((threadIdx.x & 63) == 0) atomicMax(slot, m);
}

// per-row max|W_res[n][:]| — one wave per row, plain store (deterministic)
__global__ __launch_bounds__(256) void rowmax_kernel(const float* __restrict__ W,
                                                     float* __restrict__ rowmax) {
    const int row = blockIdx.x * 4 + ((int)threadIdx.x >> 6);
    const int lane = threadIdx.x & 63;
    float m = 0.f;
    for (int j = lane; j < NRES; j += 64) m = fmaxf(m, fabsf(W[row * NRES + j]));
#pragma unroll
    for (int off = 32; off >= 1; off >>= 1) m = fmaxf(m, __shfl_xor(m, off, 64));
    if (lane == 0) rowmax[row] = m;
}

// W_res -> signed-int8 (PER-ROW scale) in MFMA B-fragment order:
// dword o4: bl=o4>>15, wv=(o4>>12)&7, kt=(o4>>8)&15, L=(o4>>2)&63, i0=(o4&3)*4
// n = bl*128+wv*16+(L&15); k = kt*64+(L>>4)*16+i0..+3; value = q(W_res[n][k])
__global__ __launch_bounds__(256) void quant_res(const float* __restrict__ W,
                                                 const float* __restrict__ rowmax,
                                                 unsigned* __restrict__ dst) {
    const int o4 = blockIdx.x * 256 + threadIdx.x;
    const int bl = o4 >> 15, wv = (o4 >> 12) & 7, kt = (o4 >> 8) & 15;
    const int L = (o4 >> 2) & 63, i0 = (o4 & 3) * 4;
    const int n = bl * 128 + wv * 16 + (L & 15);
    const int k = kt * 64 + (L >> 4) * 16 + i0;
    const float inv = 127.0f / rowmax[n];
    unsigned dw = 0;
#pragma unroll
    for (int j = 0; j < 4; ++j) {
        float q = rintf(W[n * NRES + k + j] * inv);
        q = fminf(fmaxf(q, -127.f), 127.f);
        dw |= ((unsigned)((int)q & 0xff)) << (8 * j);
    }
    dst[o4] = dw;
}

// W_clf -> int8 fragment tile (16 cols, cls>=10 zero): 4096 dwords
__global__ __launch_bounds__(256) void quant_clf(const float* __restrict__ W,
                                                 const unsigned* __restrict__ slot,
                                                 unsigned* __restrict__ dst) {
    const int o4 = blockIdx.x * 256 + threadIdx.x;
    const int kt = (o4 >> 8) & 15, L = (o4 >> 2) & 63, i0 = (o4 & 3) * 4;
    const int cls = L & 15;
    const int k = kt * 64 + (L >> 4) * 16 + i0;
    const float inv = 127.0f / __uint_as_float(*slot);
    unsigned dw = 0;
    if (cls < NCLS) {
#pragma unroll
        for (int j = 0; j < 4; ++j) {
            float q = rintf(W[cls * NRES + k + j] * inv);
            q = fminf(fmaxf(q, -127.f), 127.f);
            dw |= ((unsigned)((int)q & 0xff)) << (8 * j);
        }
    }
    dst[o4] = dw;
}

__device__ __forceinline__ unsigned short f2bf(float f) {
    unsigned u = __float_as_uint(f);
    return (unsigned short)((u + 0x7fffu + ((u >> 16) & 1u)) >> 16);
}

// ---------------------------------------------------------------------------
// 256 blocks x 512 threads (1/CU, all co-resident). Block = (group g, slot bl):
// owns 16 batch rows x 128 neurons. Per step: 8-block barrier -> read group
// spike mask (2 KB) -> expand to A (16x1024 i8, LDS) -> dense i8 MFMA against
// LDS-resident W slice (exact int, per-row dequant) + DOUBLE-BF16 input
// projection (x and W_in split hi/lo -> 2 chained bf16 MFMAs, K=32 = 16hi+16lo,
// ~2^-16 effective precision) -> LIF -> ballots -> publish mask + arrive.
// Block0/wave0 runs the classifier (deferred one step) from the same A image.
// ---------------------------------------------------------------------------
__global__ __launch_bounds__(512, 1) void reservoir_mfma(
    const float* __restrict__ x, const float* __restrict__ W_in,
    unsigned char* __restrict__ ws, float* __restrict__ out)
{
    const int g   = blockIdx.x >> 3;
    const int bl  = blockIdx.x & 7;
    const int tid = (int)threadIdx.x;
    const int L    = tid & 63;
    const int wv   = tid >> 6;     // 0..7
    const int col  = L & 15;       // MFMA n-column (neuron) for C/D
    const int rowq = L >> 4;       // row quad: batch = rowq*4 + r

    extern __shared__ char lds[];
    char* B_lds = lds;                                   // 131072 B
    char* A_lds = lds + 131072;                          // 16 x 1040 B
    unsigned short* xA = (unsigned short*)(lds + 131072 + 16 * 1040);  // 16x32 bf16 (hi|lo)

    unsigned* ctr = (unsigned*)(ws + CTR_OFF);
    const float* rowmax = (const float*)(ws + ROWMAX_OFF);
    const float cscale = __uint_as_float(*(const unsigned*)(ws + SLOTC_OFF)) * (1.0f / 127.0f);
    unsigned char* maskbuf = ws + MASK_OFF;
    const unsigned char* wqf = ws + WQF_OFF;
    const unsigned char* wcf = ws + WCF_OFF;

    const int nn = bl * 128 + wv * 16 + col;             // my output neuron
    const float dscale = rowmax[nn] * (1.0f / 127.0f);   // per-row dequant

    // ---- load my 128 KB weight slice into LDS
    {
        const v4i* src = (const v4i*)(wqf + (size_t)bl * 131072);
        v4i* dst = (v4i*)B_lds;
        for (int i = tid; i < 131072 / 16; i += 512) dst[i] = src[i];
    }

    // ---- constant W_in hi/lo bf16 B-fragments: B[k=rowq*8+i][n=col], c = k&15
    v8s binf_h, binf_l;
#pragma unroll
    for (int i = 0; i < 8; ++i) {
        const int c = (rowq * 8 + i) & 15;
        const float w = W_in[nn * CIN + c];
        const unsigned short h = f2bf(w);
        const float wl = w - __uint_as_float((unsigned)h << 16);
        binf_h[i] = (short)h;
        binf_l[i] = (short)f2bf(wl);
    }

    float v[4]  = {0.f, 0.f, 0.f, 0.f};
    int   accv[4] = {0, 0, 0, 0};
    float vc[4] = {0.f, 0.f, 0.f, 0.f};
    int   accc[4] = {0, 0, 0, 0};
    unsigned tgt[2] = {8u, 8u};
    const bool isClf = (bl == 0 && wv == 0);

    __syncthreads();

    for (int t = 0; t < TSTEPS; ++t) {
        // prefetch x_t (issue early; completes during spin)
        float xval = 0.f;
        if (tid < 256) {
            const int b = tid >> 4, c = tid & 15;
            xval = x[((size_t)(g * 16 + b) * CIN + c) * TSTEPS + t];
        }

        if (t > 0) {
            const int p = (t - 1) & 1;
            if (tid == 0) {
                unsigned* c0 = ctr + (size_t)(g * 2 + p) * 32;
                const unsigned want = tgt[p];
                while (__hip_atomic_load(c0, __ATOMIC_ACQUIRE, __HIP_MEMORY_SCOPE_AGENT) < want)
                    __builtin_amdgcn_s_sleep(2);
            }
            tgt[p] += 8;
            __syncthreads();   // all 8 blocks' masks of t-1 visible; LDS reusable

            // ---- A-build: thread (b = tid>>5, seg = tid&31) expands 32 bits -> 32 bytes
            {
                const int b = tid >> 5, seg = tid & 31;
                const unsigned* mp = (const unsigned*)(maskbuf +
                    (size_t)((p * NGROUP + g) * 16 + b) * 128 + seg * 4);
                const unsigned m = __hip_atomic_load(mp, __ATOMIC_RELAXED, __HIP_MEMORY_SCOPE_AGENT);
                unsigned* dst = (unsigned*)(A_lds + b * 1040 + seg * 32);
#pragma unroll
                for (int d = 0; d < 8; ++d) {
                    const unsigned mm = m >> (4 * d);
                    dst[d] = (mm & 1u) | ((mm & 2u) << 7) | ((mm & 4u) << 14) | ((mm & 8u) << 21);
                }
            }
        }
        // ---- stage x_t hi/lo: row b = [hi c=0..15 | lo c=0..15]
        if (tid < 256) {
            const int b = tid >> 4, c = tid & 15;
            const unsigned short h = f2bf(xval);
            const float lo = xval - __uint_as_float((unsigned)h << 16);
            xA[b * 32 + c] = h;
            xA[b * 32 + 16 + c] = f2bf(lo);
        }
        __syncthreads();   // A + xA ready

        // ---- input projection: (xh+xl).(Wh+Wl) via 2 chained bf16 MFMAs
        v4f Din;
        {
            const v8s xa = *(const v8s*)((const char*)xA + col * 64 + rowq * 16);
            v4f z = {0.f, 0.f, 0.f, 0.f};
            const v4f D1 = __builtin_amdgcn_mfma_f32_16x16x32_bf16(xa, binf_h, z, 0, 0, 0);
            Din = __builtin_amdgcn_mfma_f32_16x16x32_bf16(xa, binf_l, D1, 0, 0, 0);
        }

        // ---- recurrent: 16 x mfma_i32_16x16x64_i8 (exact int)
        v4i Drec = {0, 0, 0, 0};
        if (t > 0) {
            const char* Bb = B_lds + wv * 16384;
            const char* Ab = A_lds + col * 1040 + rowq * 16;
#pragma unroll 4
            for (int kt = 0; kt < 16; ++kt) {
                const v4i af = *(const v4i*)(Ab + kt * 64);
                const v4i bf = *(const v4i*)(Bb + kt * 1024 + L * 16);
                Drec = __builtin_amdgcn_mfma_i32_16x16x64_i8(af, bf, Drec, 0, 0, 0);
            }
        }

        // ---- classifier (block0/wave0): consumes s_{t-1} from same A image
        if (isClf && t > 0) {
            v4i Dc = {0, 0, 0, 0};
            const char* Ab = A_lds + col * 1040 + rowq * 16;
#pragma unroll 4
            for (int kt = 0; kt < 16; ++kt) {
                const v4i af = *(const v4i*)(Ab + kt * 64);
                const v4i bf = *(const v4i*)(wcf + kt * 1024 + L * 16);
                Dc = __builtin_amdgcn_mfma_i32_16x16x64_i8(af, bf, Dc, 0, 0, 0);
            }
#pragma unroll
            for (int r = 0; r < 4; ++r) {
                const float vcn = ALPHA * vc[r] + cscale * (float)Dc[r];
                const int sc = (vcn >= THRESH);
                accc[r] += sc;
                vc[r] = sc ? 0.f : vcn;
            }
        }

        // ---- LIF update + spikes + ballots
        unsigned long long bal0, bal1, bal2, bal3;
        {
            float vn; int s;
            vn = ALPHA * v[0] + Din[0] + dscale * (float)Drec[0];
            s = (vn >= THRESH); accv[0] += s; v[0] = s ? 0.f : vn; bal0 = __ballot(s);
            vn = ALPHA * v[1] + Din[1] + dscale * (float)Drec[1];
            s = (vn >= THRESH); accv[1] += s; v[1] = s ? 0.f : vn; bal1 = __ballot(s);
            vn = ALPHA * v[2] + Din[2] + dscale * (float)Drec[2];
            s = (vn >= THRESH); accv[2] += s; v[2] = s ? 0.f : vn; bal2 = __ballot(s);
            vn = ALPHA * v[3] + Din[3] + dscale * (float)Drec[3];
            s = (vn >= THRESH); accv[3] += s; v[3] = s ? 0.f : vn; bal3 = __ballot(s);
        }

        // ---- publish: lanes 0..15 write batch L's 16-neuron field for this wave
        {
            const int p = t & 1;
            if (L < 16) {
                const int b = L;
                unsigned long long bb = (b & 2) ? ((b & 1) ? bal3 : bal2)
                                                : ((b & 1) ? bal1 : bal0);
                const unsigned short fld = (unsigned short)((bb >> ((b >> 2) * 16)) & 0xFFFFu);
                unsigned short* mp = (unsigned short*)(maskbuf +
                    (size_t)((p * NGROUP + g) * 16 + b) * 128 + (bl * 8 + wv) * 2);
                __hip_atomic_store(mp, fld, __ATOMIC_RELAXED, __HIP_MEMORY_SCOPE_AGENT);
            }
        }
        __threadfence();
        __syncthreads();
        if (tid == 0)
            __hip_atomic_fetch_add(ctr + (size_t)(g * 2 + (t & 1)) * 32, 1u,
                                   __ATOMIC_RELEASE, __HIP_MEMORY_SCOPE_AGENT);
    }

    // ---- epilogue: classifier flush for s_{TSTEPS-1} (parity 1) + outputs
    if (bl == 0) {
        if (tid == 0) {
            unsigned* c0 = ctr + (size_t)(g * 2 + 1) * 32;
            const unsigned want = tgt[1];
            while (__hip_atomic_load(c0, __ATOMIC_ACQUIRE, __HIP_MEMORY_SCOPE_AGENT) < want)
                __builtin_amdgcn_s_sleep(2);
        }
        __syncthreads();
        {
            const int b = tid >> 5, seg = tid & 31;
            const unsigned* mp = (const unsigned*)(maskbuf +
                (size_t)((1 * NGROUP + g) * 16 + b) * 128 + seg * 4);
            const unsigned m = __hip_atomic_load(mp, __ATOMIC_RELAXED, __HIP_MEMORY_SCOPE_AGENT);
            unsigned* dst = (unsigned*)(A_lds + b * 1040 + seg * 32);
#pragma unroll
            for (int d = 0; d < 8; ++d) {
                const unsigned mm = m >> (4 * d);
                dst[d] = (mm & 1u) | ((mm & 2u) << 7) | ((mm & 4u) << 14) | ((mm & 8u) << 21);
            }
        }
        __syncthreads();
        if (wv == 0) {
            v4i Dc = {0, 0, 0, 0};
            const char* Ab = A_lds + col * 1040 + rowq * 16;
#pragma unroll 4
            for (int kt = 0; kt < 16; ++kt) {
                const v4i af = *(const v4i*)(Ab + kt * 64);
                const v4i bf = *(const v4i*)(wcf + kt * 1024 + L * 16);
                Dc = __builtin_amdgcn_mfma_i32_16x16x64_i8(af, bf, Dc, 0, 0, 0);
            }
            if (col < NCLS) {
#pragma unroll
                for (int r = 0; r < 4; ++r) {
                    const float vcn = ALPHA * vc[r] + cscale * (float)Dc[r];
                    const int sc = (vcn >= THRESH);
                    out[(size_t)(g * 16 + rowq * 4 + r) * NCLS + col] = (float)(accc[r] + sc);
                }
            }
        }
    }
    {
#pragma unroll
        for (int r = 0; r < 4; ++r) {
            const int bglob = g * 16 + rowq * 4 + r;
            out[BATCH * NCLS + (size_t)bglob * NRES + nn] = (float)accv[r];
        }
    }
}

extern "C" void kernel_launch(void* const* d_in, const int* in_sizes, int n_in,
                              void* d_out, int out_size, void* d_ws, size_t ws_size,
                              hipStream_t stream) {
    (void)in_sizes; (void)n_in; (void)out_size; (void)ws_size;
    const float* x     = (const float*)d_in[0];
    const float* W_in  = (const float*)d_in[1];
    const float* W_res = (const float*)d_in[2];
    const float* W_clf = (const float*)d_in[3];
    float* out = (float*)d_out;
    unsigned char* ws = (unsigned char*)d_ws;

    hipMemsetAsync(ws, 0, 16384, stream);  // barrier counters + clf slot + rowmax
    rowmax_kernel<<<256, 256, 0, stream>>>(W_res, (float*)(ws + ROWMAX_OFF));
    maxabs_kernel<<<16, 256, 0, stream>>>(W_clf, NCLS * NRES, (unsigned*)(ws + SLOTC_OFF));
    quant_res<<<1024, 256, 0, stream>>>(W_res, (const float*)(ws + ROWMAX_OFF),
                                        (unsigned*)(ws + WQF_OFF));
    quant_clf<<<16, 256, 0, stream>>>(W_clf, (const unsigned*)(ws + SLOTC_OFF),
                                      (unsigned*)(ws + WCF_OFF));
    reservoir_mfma<<<NGROUP * BPG, 512, LDS_BYTES, stream>>>(x, W_in, ws, out);
}

// Round 7
// 8331.360 us; speedup vs baseline: 9.4082x; 9.4082x over previous
//
#include <hip/hip_runtime.h>

#define ALPHA 0.9f
#define THRESH 1.0f
#define BATCH 512
#define CIN 16
#define TSTEPS 2000
#define NRES 1024
#define NCLS 10

#define NGROUP 32       // 32 batch groups of 16 rows
#define BPG 8           // blocks per group, 128 neurons each

typedef int   v4i __attribute__((ext_vector_type(4)));
typedef float v4f __attribute__((ext_vector_type(4)));
typedef short v8s __attribute__((ext_vector_type(8)));

// ---- ws layout (bytes) ----
#define CTR_OFF    0        // 32 groups x 2 parities x 128 B barrier counters (8 KB)
#define SLOTC_OFF  8192     // max|W_clf| bits
#define ROWMAX_OFF 9216     // per-row max|W_res[n][:]|, 1024 floats (4 KB)
#define MASK_OFF   16384    // spike masks: 2 x 32 x 16 x 128 B = 128 KB
#define WQF_OFF    147456   // W_res int8, MFMA-fragment order: 1 MB
#define WCF_OFF    1196032  // W_clf int8 fragment tile: 16 KB
#define LDS_BYTES  (131072 + 16*1040 + 1024)   // B slice + A image + xA image

__global__ __launch_bounds__(256) void maxabs_kernel(const float* __restrict__ W,
                                                     int n, unsigned* __restrict__ slot) {
    unsigned m = 0u;
    for (int i = blockIdx.x * 256 + threadIdx.x; i < n; i += gridDim.x * 256)
        m = max(m, __float_as_uint(W[i]) & 0x7fffffffu);
#pragma unroll
    for (int off = 32; off >= 1; off >>= 1)
        m = max(m, (unsigned)__shfl_xor((int)m, off, 64));
    if ((threadIdx.x & 63) == 0) atomicMax(slot, m);
}

// per-row max|W_res[n][:]| — one wave per row, plain store (deterministic)
__global__ __launch_bounds__(256) void rowmax_kernel(const float* __restrict__ W,
                                                     float* __restrict__ rowmax) {
    const int row = blockIdx.x * 4 + ((int)threadIdx.x >> 6);
    const int lane = threadIdx.x & 63;
    float m = 0.f;
    for (int j = lane; j < NRES; j += 64) m = fmaxf(m, fabsf(W[row * NRES + j]));
#pragma unroll
    for (int off = 32; off >= 1; off >>= 1) m = fmaxf(m, __shfl_xor(m, off, 64));
    if (lane == 0) rowmax[row] = m;
}

// W_res -> signed-int8 (PER-ROW scale) in MFMA B-fragment order:
// dword o4: bl=o4>>15, wv=(o4>>12)&7, kt=(o4>>8)&15, L=(o4>>2)&63, i0=(o4&3)*4
// n = bl*128+wv*16+(L&15); k = kt*64+(L>>4)*16+i0..+3; value = q(W_res[n][k])
__global__ __launch_bounds__(256) void quant_res(const float* __restrict__ W,
                                                 const float* __restrict__ rowmax,
                                                 unsigned* __restrict__ dst) {
    const int o4 = blockIdx.x * 256 + threadIdx.x;
    const int bl = o4 >> 15, wv = (o4 >> 12) & 7, kt = (o4 >> 8) & 15;
    const int L = (o4 >> 2) & 63, i0 = (o4 & 3) * 4;
    const int n = bl * 128 + wv * 16 + (L & 15);
    const int k = kt * 64 + (L >> 4) * 16 + i0;
    const float inv = 127.0f / rowmax[n];
    unsigned dw = 0;
#pragma unroll
    for (int j = 0; j < 4; ++j) {
        float q = rintf(W[n * NRES + k + j] * inv);
        q = fminf(fmaxf(q, -127.f), 127.f);
        dw |= ((unsigned)((int)q & 0xff)) << (8 * j);
    }
    dst[o4] = dw;
}

// W_clf -> int8 fragment tile (16 cols, cls>=10 zero): 4096 dwords
__global__ __launch_bounds__(256) void quant_clf(const float* __restrict__ W,
                                                 const unsigned* __restrict__ slot,
                                                 unsigned* __restrict__ dst) {
    const int o4 = blockIdx.x * 256 + threadIdx.x;
    const int kt = (o4 >> 8) & 15, L = (o4 >> 2) & 63, i0 = (o4 & 3) * 4;
    const int cls = L & 15;
    const int k = kt * 64 + (L >> 4) * 16 + i0;
    const float inv = 127.0f / __uint_as_float(*slot);
    unsigned dw = 0;
    if (cls < NCLS) {
#pragma unroll
        for (int j = 0; j < 4; ++j) {
            float q = rintf(W[cls * NRES + k + j] * inv);
            q = fminf(fmaxf(q, -127.f), 127.f);
            dw |= ((unsigned)((int)q & 0xff)) << (8 * j);
        }
    }
    dst[o4] = dw;
}

__device__ __forceinline__ unsigned short f2bf(float f) {
    unsigned u = __float_as_uint(f);
    return (unsigned short)((u + 0x7fffu + ((u >> 16) & 1u)) >> 16);
}

// ---------------------------------------------------------------------------
// 256 blocks x 512 threads (1/CU). Block = (group g, slot bl): 16 batch rows
// x 128 neurons, int8 W slice LDS-resident. Per step: relaxed spin on the
// group counter (agent-scope ops bypass L2 -> always fresh; NO acquire/release
// fences, so no buffer_wbl2/inv storms) -> read group mask -> expand to A ->
// i8 MFMAs (exact, per-row dequant) + double-bf16 input MFMAs -> LIF ->
// ballots -> publish mask (agent relaxed) -> __syncthreads (drains stores:
// compiler emits vmcnt(0) before s_barrier) -> relaxed arrival add.
// Group's 8 blocks co-located on one XCD via blockIdx swizzle (speed only).
// ---------------------------------------------------------------------------
__global__ __launch_bounds__(512, 1) void reservoir_mfma(
    const float* __restrict__ x, const float* __restrict__ W_in,
    unsigned char* __restrict__ ws, float* __restrict__ out)
{
    // XCD co-location: q%8 = XCD (dispatch heuristic). Group g -> 8 blocks
    // with identical q%8. Bijection: g = (q&7)*4 + ((q>>3)&3), bl = q>>5.
    const int q   = (int)blockIdx.x;
    const int g   = (q & 7) * 4 + ((q >> 3) & 3);
    const int bl  = q >> 5;
    const int tid = (int)threadIdx.x;
    const int L    = tid & 63;
    const int wv   = tid >> 6;     // 0..7
    const int col  = L & 15;       // MFMA n-column (neuron) for C/D
    const int rowq = L >> 4;       // row quad: batch = rowq*4 + r

    extern __shared__ char lds[];
    char* B_lds = lds;                                   // 131072 B
    char* A_lds = lds + 131072;                          // 16 x 1040 B
    unsigned short* xA = (unsigned short*)(lds + 131072 + 16 * 1040);  // 16x32 bf16 (hi|lo)

    unsigned* ctr = (unsigned*)(ws + CTR_OFF);
    const float* rowmax = (const float*)(ws + ROWMAX_OFF);
    const float cscale = __uint_as_float(*(const unsigned*)(ws + SLOTC_OFF)) * (1.0f / 127.0f);
    unsigned char* maskbuf = ws + MASK_OFF;
    const unsigned char* wqf = ws + WQF_OFF;
    const unsigned char* wcf = ws + WCF_OFF;

    const int nn = bl * 128 + wv * 16 + col;             // my output neuron
    const float dscale = rowmax[nn] * (1.0f / 127.0f);   // per-row dequant

    // ---- load my 128 KB weight slice into LDS
    {
        const v4i* src = (const v4i*)(wqf + (size_t)bl * 131072);
        v4i* dst = (v4i*)B_lds;
        for (int i = tid; i < 131072 / 16; i += 512) dst[i] = src[i];
    }

    // ---- constant W_in hi/lo bf16 B-fragments: B[k=rowq*8+i][n=col], c = k&15
    v8s binf_h, binf_l;
#pragma unroll
    for (int i = 0; i < 8; ++i) {
        const int c = (rowq * 8 + i) & 15;
        const float w = W_in[nn * CIN + c];
        const unsigned short h = f2bf(w);
        const float wl = w - __uint_as_float((unsigned)h << 16);
        binf_h[i] = (short)h;
        binf_l[i] = (short)f2bf(wl);
    }

    float v[4]  = {0.f, 0.f, 0.f, 0.f};
    int   accv[4] = {0, 0, 0, 0};
    float vc[4] = {0.f, 0.f, 0.f, 0.f};
    int   accc[4] = {0, 0, 0, 0};
    unsigned tgt[2] = {8u, 8u};
    const bool isClf = (bl == 0 && wv == 0);

    __syncthreads();

    for (int t = 0; t < TSTEPS; ++t) {
        // prefetch x_t (issued early; completes during spin)
        float xval = 0.f;
        if (tid < 256) {
            const int b = tid >> 4, c = tid & 15;
            xval = x[((size_t)(g * 16 + b) * CIN + c) * TSTEPS + t];
        }

        if (t > 0) {
            const int p = (t - 1) & 1;
            if (tid == 0) {
                unsigned* c0 = ctr + (size_t)(g * 2 + p) * 32;
                const unsigned want = tgt[p];
                // RELAXED spin: bypassing load reads coherence point, no buffer_inv
                while (__hip_atomic_load(c0, __ATOMIC_RELAXED, __HIP_MEMORY_SCOPE_AGENT) < want)
                    __builtin_amdgcn_s_sleep(1);
            }
            tgt[p] += 8;
            __syncthreads();   // all 8 blocks' masks of t-1 visible; LDS reusable

            // ---- A-build: thread (b = tid>>5, seg = tid&31): 32 bits -> 32 bytes,
            //      written as 2x ds_write_b128 (conflict-free uniform bank spread)
            {
                const int b = tid >> 5, seg = tid & 31;
                const unsigned* mp = (const unsigned*)(maskbuf +
                    (size_t)((p * NGROUP + g) * 16 + b) * 128 + seg * 4);
                const unsigned m = __hip_atomic_load(mp, __ATOMIC_RELAXED, __HIP_MEMORY_SCOPE_AGENT);
                unsigned w[8];
#pragma unroll
                for (int d = 0; d < 8; ++d) {
                    const unsigned mm = m >> (4 * d);
                    w[d] = (mm & 1u) | ((mm & 2u) << 7) | ((mm & 4u) << 14) | ((mm & 8u) << 21);
                }
                v4i* dst = (v4i*)(A_lds + b * 1040 + seg * 32);
                dst[0] = *(v4i*)&w[0];
                dst[1] = *(v4i*)&w[4];
            }
        }
        // ---- stage x_t hi/lo: row b = [hi c=0..15 | lo c=0..15]
        if (tid < 256) {
            const int b = tid >> 4, c = tid & 15;
            const unsigned short h = f2bf(xval);
            const float lo = xval - __uint_as_float((unsigned)h << 16);
            xA[b * 32 + c] = h;
            xA[b * 32 + 16 + c] = f2bf(lo);
        }
        __syncthreads();   // A + xA ready

        // ---- input projection: (xh+xl).(Wh+Wl) via 2 chained bf16 MFMAs
        v4f Din;
        {
            const v8s xa = *(const v8s*)((const char*)xA + col * 64 + rowq * 16);
            v4f z = {0.f, 0.f, 0.f, 0.f};
            const v4f D1 = __builtin_amdgcn_mfma_f32_16x16x32_bf16(xa, binf_h, z, 0, 0, 0);
            Din = __builtin_amdgcn_mfma_f32_16x16x32_bf16(xa, binf_l, D1, 0, 0, 0);
        }

        // ---- recurrent: 16 x mfma_i32_16x16x64_i8 (exact int)
        v4i Drec = {0, 0, 0, 0};
        if (t > 0) {
            const char* Bb = B_lds + wv * 16384;
            const char* Ab = A_lds + col * 1040 + rowq * 16;
#pragma unroll 4
            for (int kt = 0; kt < 16; ++kt) {
                const v4i af = *(const v4i*)(Ab + kt * 64);
                const v4i bf = *(const v4i*)(Bb + kt * 1024 + L * 16);
                Drec = __builtin_amdgcn_mfma_i32_16x16x64_i8(af, bf, Drec, 0, 0, 0);
            }
        }

        // ---- classifier (block0/wave0): consumes s_{t-1} from same A image
        if (isClf && t > 0) {
            v4i Dc = {0, 0, 0, 0};
            const char* Ab = A_lds + col * 1040 + rowq * 16;
#pragma unroll 4
            for (int kt = 0; kt < 16; ++kt) {
                const v4i af = *(const v4i*)(Ab + kt * 64);
                const v4i bf = *(const v4i*)(wcf + kt * 1024 + L * 16);
                Dc = __builtin_amdgcn_mfma_i32_16x16x64_i8(af, bf, Dc, 0, 0, 0);
            }
#pragma unroll
            for (int r = 0; r < 4; ++r) {
                const float vcn = ALPHA * vc[r] + cscale * (float)Dc[r];
                const int sc = (vcn >= THRESH);
                accc[r] += sc;
                vc[r] = sc ? 0.f : vcn;
            }
        }

        // ---- LIF update + spikes + ballots
        unsigned long long bal0, bal1, bal2, bal3;
        {
            float vn; int s;
            vn = ALPHA * v[0] + Din[0] + dscale * (float)Drec[0];
            s = (vn >= THRESH); accv[0] += s; v[0] = s ? 0.f : vn; bal0 = __ballot(s);
            vn = ALPHA * v[1] + Din[1] + dscale * (float)Drec[1];
            s = (vn >= THRESH); accv[1] += s; v[1] = s ? 0.f : vn; bal1 = __ballot(s);
            vn = ALPHA * v[2] + Din[2] + dscale * (float)Drec[2];
            s = (vn >= THRESH); accv[2] += s; v[2] = s ? 0.f : vn; bal2 = __ballot(s);
            vn = ALPHA * v[3] + Din[3] + dscale * (float)Drec[3];
            s = (vn >= THRESH); accv[3] += s; v[3] = s ? 0.f : vn; bal3 = __ballot(s);
        }

        // ---- publish: lanes 0..15 write batch L's 16-neuron field (agent relaxed)
        {
            const int p = t & 1;
            if (L < 16) {
                const int b = L;
                unsigned long long bb = (b & 2) ? ((b & 1) ? bal3 : bal2)
                                                : ((b & 1) ? bal1 : bal0);
                const unsigned short fld = (unsigned short)((bb >> ((b >> 2) * 16)) & 0xFFFFu);
                unsigned short* mp = (unsigned short*)(maskbuf +
                    (size_t)((p * NGROUP + g) * 16 + b) * 128 + (bl * 8 + wv) * 2);
                __hip_atomic_store(mp, fld, __ATOMIC_RELAXED, __HIP_MEMORY_SCOPE_AGENT);
            }
        }
        // __syncthreads drains each wave's stores (compiler emits vmcnt(0) before
        // s_barrier), so all bypassing mask stores are at the coherence point
        // before the arrival add below. No fence -> no buffer_wbl2.
        __syncthreads();
        if (tid == 0) {
            asm volatile("s_waitcnt vmcnt(0) lgkmcnt(0)" ::: "memory");
            __hip_atomic_fetch_add(ctr + (size_t)(g * 2 + (t & 1)) * 32, 1u,
                                   __ATOMIC_RELAXED, __HIP_MEMORY_SCOPE_AGENT);
        }
    }

    // ---- epilogue: classifier flush for s_{TSTEPS-1} (parity 1) + outputs
    if (bl == 0) {
        if (tid == 0) {
            unsigned* c0 = ctr + (size_t)(g * 2 + 1) * 32;
            const unsigned want = tgt[1];
            while (__hip_atomic_load(c0, __ATOMIC_RELAXED, __HIP_MEMORY_SCOPE_AGENT) < want)
                __builtin_amdgcn_s_sleep(1);
        }
        __syncthreads();
        {
            const int b = tid >> 5, seg = tid & 31;
            const unsigned* mp = (const unsigned*)(maskbuf +
                (size_t)((1 * NGROUP + g) * 16 + b) * 128 + seg * 4);
            const unsigned m = __hip_atomic_load(mp, __ATOMIC_RELAXED, __HIP_MEMORY_SCOPE_AGENT);
            unsigned w[8];
#pragma unroll
            for (int d = 0; d < 8; ++d) {
                const unsigned mm = m >> (4 * d);
                w[d] = (mm & 1u) | ((mm & 2u) << 7) | ((mm & 4u) << 14) | ((mm & 8u) << 21);
            }
            v4i* dst = (v4i*)(A_lds + b * 1040 + seg * 32);
            dst[0] = *(v4i*)&w[0];
            dst[1] = *(v4i*)&w[4];
        }
        __syncthreads();
        if (wv == 0) {
            v4i Dc = {0, 0, 0, 0};
            const char* Ab = A_lds + col * 1040 + rowq * 16;
#pragma unroll 4
            for (int kt = 0; kt < 16; ++kt) {
                const v4i af = *(const v4i*)(Ab + kt * 64);
                const v4i bf = *(const v4i*)(wcf + kt * 1024 + L * 16);
                Dc = __builtin_amdgcn_mfma_i32_16x16x64_i8(af, bf, Dc, 0, 0, 0);
            }
            if (col < NCLS) {
#pragma unroll
                for (int r = 0; r < 4; ++r) {
                    const float vcn = ALPHA * vc[r] + cscale * (float)Dc[r];
                    const int sc = (vcn >= THRESH);
                    out[(size_t)(g * 16 + rowq * 4 + r) * NCLS + col] = (float)(accc[r] + sc);
                }
            }
        }
    }
    {
#pragma unroll
        for (int r = 0; r < 4; ++r) {
            const int bglob = g * 16 + rowq * 4 + r;
            out[BATCH * NCLS + (size_t)bglob * NRES + nn] = (float)accv[r];
        }
    }
}

extern "C" void kernel_launch(void* const* d_in, const int* in_sizes, int n_in,
                              void* d_out, int out_size, void* d_ws, size_t ws_size,
                              hipStream_t stream) {
    (void)in_sizes; (void)n_in; (void)out_size; (void)ws_size;
    const float* x     = (const float*)d_in[0];
    const float* W_in  = (const float*)d_in[1];
    const float* W_res = (const float*)d_in[2];
    const float* W_clf = (const float*)d_in[3];
    float* out = (float*)d_out;
    unsigned char* ws = (unsigned char*)d_ws;

    hipMemsetAsync(ws, 0, 16384, stream);  // barrier counters + clf slot + rowmax
    rowmax_kernel<<<256, 256, 0, stream>>>(W_res, (float*)(ws + ROWMAX_OFF));
    maxabs_kernel<<<16, 256, 0, stream>>>(W_clf, NCLS * NRES, (unsigned*)(ws + SLOTC_OFF));
    quant_res<<<1024, 256, 0, stream>>>(W_res, (const float*)(ws + ROWMAX_OFF),
                                        (unsigned*)(ws + WQF_OFF));
    quant_clf<<<16, 256, 0, stream>>>(W_clf, (const unsigned*)(ws + SLOTC_OFF),
                                      (unsigned*)(ws + WCF_OFF));
    reservoir_mfma<<<NGROUP * BPG, 512, LDS_BYTES, stream>>>(x, W_in, ws, out);
}